// Round 1
// baseline (2612.592 us; speedup 1.0000x reference)
//
#include <hip/hip_runtime.h>
#include <cstdint>
#include <cstddef>

// RNNQNetwork: MLP encoder (bf16 MFMA GEMMs) -> 128-step GRU scan
// (weight-stationary-in-VGPR distributed GEMM + per-row-group flag barriers)
// -> output head GEMM.
//
// T=128, B=512, H=512, ACTION_DIM=18. All matmul compute in bf16 MFMA
// (16x16x32), fp32 accumulate; threshold 5e-2 permits bf16 intermediates.

#define TT 128
#define BBATCH 512
#define HH 512
#define MM 65536   // T*B
#define AD 18

typedef __attribute__((ext_vector_type(8))) short short8;
typedef __attribute__((ext_vector_type(4))) float float4v;
typedef __attribute__((ext_vector_type(4))) unsigned int uint4v;

__device__ __forceinline__ unsigned short f2bf(float f) {
  union { float f; unsigned int u; } v; v.f = f;
  unsigned int r = v.u + 0x7fffu + ((v.u >> 16) & 1u);  // RNE
  return (unsigned short)(r >> 16);
}
__device__ __forceinline__ float bf2f(unsigned short h) {
  union { unsigned int u; float f; } v; v.u = ((unsigned int)h) << 16;
  return v.f;
}

// async global->LDS, 16B per lane. LDS dest must be wave-uniform base;
// lanes deposit at base + lane*16 (guide section 5 caveat).
typedef __attribute__((address_space(3))) unsigned int* lds_u32p;
typedef const __attribute__((address_space(1))) unsigned int* glb_u32p;
__device__ __forceinline__ void async16(void* lds, const void* g) {
  __builtin_amdgcn_global_load_lds(
      (glb_u32p)(unsigned long long)g,
      (lds_u32p)(unsigned int)(unsigned long long)lds, 16, 0, 0);
}

// ---------------- prep kernels ----------------

// obs fp32 -> bf16 (packed 4/thread); also zero the dones-format flag.
__global__ __launch_bounds__(256) void k_conv_obs(
    const float* __restrict__ src, unsigned short* __restrict__ dst,
    unsigned int* __restrict__ flag) {
  if (blockIdx.x == 0 && threadIdx.x == 0) *flag = 0u;
  int i = blockIdx.x * 256 + threadIdx.x;      // grid sized exactly
  float4v v = ((const float4v*)src)[i];
  unsigned long long pk = (unsigned long long)f2bf(v[0])
      | ((unsigned long long)f2bf(v[1]) << 16)
      | ((unsigned long long)f2bf(v[2]) << 32)
      | ((unsigned long long)f2bf(v[3]) << 48);
  ((unsigned long long*)dst)[i] = pk;
}

// Transpose [512][512] fp32 weights -> [N][K] bf16 (B^T layout for gemm_bt).
// z: 0=w0(first 512 rows), 1=w1, 2=w_ir, 3=w_iz, 4=w_in (into Wi_t slabs).
__global__ __launch_bounds__(256) void k_prep_t(
    const float* __restrict__ w0, const float* __restrict__ w1,
    const float* __restrict__ wir, const float* __restrict__ wiz,
    const float* __restrict__ win,
    unsigned short* __restrict__ W0at, unsigned short* __restrict__ W1t,
    unsigned short* __restrict__ Wit) {
  int o = blockIdx.x * 256 + threadIdx.x;  // o = n*512 + k
  int n = o >> 9, k = o & 511;
  int z = blockIdx.y;
  const float* s = (z == 0) ? w0 : (z == 1) ? w1 : (z == 2) ? wir
                 : (z == 3) ? wiz : win;
  unsigned short b = f2bf(s[k * 512 + n]);
  if (z == 0) W0at[o] = b;
  else if (z == 1) W1t[o] = b;
  else Wit[(size_t)(z - 2) * 262144 + o] = b;
}

// Hidden weights [w_hr|w_hz|w_hn] -> MFMA-B-fragment layout:
// Whf unit (k>>3)*1536 + n holds bf16 W[k0..k0+8][n] contiguously (16B).
__global__ __launch_bounds__(256) void k_prep_whf(
    const float* __restrict__ whr, const float* __restrict__ whz,
    const float* __restrict__ whn, unsigned short* __restrict__ Whf) {
  int i = blockIdx.x * 256 + threadIdx.x;  // < 512*1536, grid exact
  int k = i / 1536, n = i - k * 1536;
  const float* s = (n < 512) ? whr : (n < 1024) ? whz : whn;
  float v = s[k * 512 + (n & 511)];
  Whf[((size_t)(k >> 3) * 1536 + n) * 8 + (k & 7)] = f2bf(v);
}

// Misc: w0 action rows (bf16), combined gru-input bias, w_out^T padded to 64,
// initial h (bf16, parity 0), zero barrier counters, detect dones dtype.
__global__ __launch_bounds__(256) void k_prep_misc(
    const float* __restrict__ w0, const float* __restrict__ bir,
    const float* __restrict__ biz, const float* __restrict__ bin,
    const float* __restrict__ wout, const float* __restrict__ hidden,
    const int* __restrict__ dI,
    unsigned short* __restrict__ w0act, float* __restrict__ gib,
    unsigned short* __restrict__ WoutT, unsigned short* __restrict__ hbuf,
    unsigned int* __restrict__ ready, unsigned int* __restrict__ flag) {
  int i = blockIdx.x * 256 + threadIdx.x;  // grid 1024 -> i < 262144
  if (i < 9216) {
    int a = i >> 9, n = i & 511;
    w0act[i] = f2bf(w0[(512 + a) * 512 + n]);
  }
  if (i < 1536)
    gib[i] = (i < 512) ? bir[i] : (i < 1024) ? biz[i - 512] : bin[i - 1024];
  if (i < 32768) {
    int n = i >> 9, k = i & 511;
    WoutT[i] = f2bf(n < AD ? wout[k * AD + n] : 0.f);
  }
  if (i < 262144) hbuf[i] = f2bf(hidden[i]);
  if (i < 1040) ready[i] = 0u;
  // dones dtype probe: first 64KB viewed as int32. int32 bools are only
  // {0,1}; packed byte-bools produce values with bits above bit0.
  if (i < 16384) { if (dI[i] & 0xFFFFFFFE) atomicOr(flag, 1u); }
}

// ---------------- phase A: GEMM C = A @ B^T (+bias [+one-hot gather]) ------

template <int MODE>  // MODE 1: add gathered w0 action row (GEMM1)
__global__ __launch_bounds__(256) void k_gemm_bt(
    const unsigned short* __restrict__ Ab,   // [M][512] bf16
    const unsigned short* __restrict__ Btb,  // [N][512] bf16
    unsigned short* __restrict__ Cb,         // [M][Ndim] bf16
    int Ndim, const float* __restrict__ bias,
    const unsigned short* __restrict__ gW,   // [18][512] bf16
    const int* __restrict__ acts) {
  // chunk-major LDS tiles: unit u = chunk*128 + row, 16B per unit (8 bf16 of k)
  __shared__ unsigned short As[4096];
  __shared__ unsigned short Bs[4096];
  const int tid = threadIdx.x, wave = tid >> 6, lane = tid & 63;
  const int quad = lane >> 4, l15 = lane & 15;
  const int m0 = blockIdx.x * 128, n0 = blockIdx.y * 128;
  const int mblk = (wave & 1) * 64, nblk = (wave >> 1) * 64;

  float4v acc[4][4];
#pragma unroll
  for (int a = 0; a < 4; ++a)
#pragma unroll
    for (int b = 0; b < 4; ++b) acc[a][b] = (float4v){0.f, 0.f, 0.f, 0.f};

  for (int k0 = 0; k0 < 512; k0 += 32) {
#pragma unroll
    for (int r = 0; r < 2; ++r) {
      int u = r * 256 + wave * 64 + lane;
      int ch = u >> 7, mm = u & 127;
      async16(&As[(size_t)(r * 256 + wave * 64) * 8],
              Ab + (size_t)(m0 + mm) * 512 + k0 + ch * 8);
      async16(&Bs[(size_t)(r * 256 + wave * 64) * 8],
              Btb + (size_t)(n0 + mm) * 512 + k0 + ch * 8);
    }
    __syncthreads();  // compiler drains vmcnt before s_barrier
    short8 afr[4], bfr[4];
#pragma unroll
    for (int mi = 0; mi < 4; ++mi)
      afr[mi] = *(const short8*)&As[((quad << 7) + mblk + mi * 16 + l15) * 8];
#pragma unroll
    for (int ni = 0; ni < 4; ++ni)
      bfr[ni] = *(const short8*)&Bs[((quad << 7) + nblk + ni * 16 + l15) * 8];
#pragma unroll
    for (int mi = 0; mi < 4; ++mi)
#pragma unroll
      for (int ni = 0; ni < 4; ++ni)
        acc[mi][ni] = __builtin_amdgcn_mfma_f32_16x16x32_bf16(
            afr[mi], bfr[ni], acc[mi][ni], 0, 0, 0);
    __syncthreads();
  }

#pragma unroll
  for (int mi = 0; mi < 4; ++mi) {
#pragma unroll
    for (int i = 0; i < 4; ++i) {
      int row = m0 + mblk + mi * 16 + quad * 4 + i;
      int arow = (MODE == 1) ? acts[row] : 0;
#pragma unroll
      for (int ni = 0; ni < 4; ++ni) {
        int col = n0 + nblk + ni * 16 + l15;
        float v = acc[mi][ni][i] + bias[col];
        if (MODE == 1) v += bf2f(gW[arow * 512 + col]);
        Cb[(size_t)row * Ndim + col] = f2bf(v);
      }
    }
  }
}

// ---------------- LayerNorm(+bias already applied) + ReLU, bf16->bf16 -------

__global__ __launch_bounds__(256) void k_ln_relu(
    const unsigned short* __restrict__ X, unsigned short* __restrict__ Y,
    const float* __restrict__ sc, const float* __restrict__ bi) {
  int row = blockIdx.x * 4 + (threadIdx.x >> 6);  // one wave per row
  int lane = threadIdx.x & 63;
  uint4v u = *(const uint4v*)(X + (size_t)row * 512 + lane * 8);
  float v[8];
#pragma unroll
  for (int j = 0; j < 4; ++j) {
    v[2 * j] = bf2f((unsigned short)(u[j] & 0xffffu));
    v[2 * j + 1] = bf2f((unsigned short)(u[j] >> 16));
  }
  float s = 0.f, q = 0.f;
#pragma unroll
  for (int j = 0; j < 8; ++j) { s += v[j]; q += v[j] * v[j]; }
#pragma unroll
  for (int d = 1; d < 64; d <<= 1) {
    s += __shfl_xor(s, d, 64);
    q += __shfl_xor(q, d, 64);
  }
  float mean = s * (1.f / 512.f);
  float var = fmaxf(q * (1.f / 512.f) - mean * mean, 0.f);
  float rstd = rsqrtf(var + 1e-6f);
  float4v s0 = *(const float4v*)(sc + lane * 8);
  float4v s1 = *(const float4v*)(sc + lane * 8 + 4);
  float4v c0 = *(const float4v*)(bi + lane * 8);
  float4v c1 = *(const float4v*)(bi + lane * 8 + 4);
  uint4v w;
#pragma unroll
  for (int j = 0; j < 4; ++j) {
    float a0 = fmaxf((v[2 * j] - mean) * rstd * (j < 2 ? s0[2 * j] : s1[2 * j - 4])
                         + (j < 2 ? c0[2 * j] : c1[2 * j - 4]), 0.f);
    float a1 = fmaxf((v[2 * j + 1] - mean) * rstd
                         * (j < 2 ? s0[2 * j + 1] : s1[2 * j - 3])
                         + (j < 2 ? c0[2 * j + 1] : c1[2 * j - 3]), 0.f);
    w[j] = (unsigned int)f2bf(a0) | ((unsigned int)f2bf(a1) << 16);
  }
  *(uint4v*)(Y + (size_t)row * 512 + lane * 8) = w;
}

// ---------------- phase B: GRU scan -----------------------------------------
// 256 blocks (8 row-groups x 32 col-chunks) x 256 threads, all co-resident by
// capacity (1 block/CU). Each wave: 16 h-rows x 16 cols x 3 gates.
// Hidden weights live in VGPRs (192 VGPR/lane) for the whole scan.
// Per-row-group barrier: 32 producers release-add a counter; consumers poll
// with agent-scope relaxed atomic loads, then agent acquire fence
// (buffer_inv handles cross-XCD L2 non-coherence).

__global__ __launch_bounds__(256, 1) void k_gru(
    const unsigned short* __restrict__ Whf, const unsigned short* __restrict__ gin,
    const float* __restrict__ bhn, const int* __restrict__ dI,
    const unsigned char* __restrict__ dB, const unsigned int* __restrict__ flag,
    unsigned short* __restrict__ hbuf, unsigned short* __restrict__ ybuf,
    float* __restrict__ outh, unsigned int* __restrict__ ready) {
  const int tid = threadIdx.x, wave = tid >> 6, lane = tid & 63;
  const int quad = lane >> 4, l15 = lane & 15;
  const int rt = blockIdx.x >> 5;   // row group (64 rows)
  const int cc = blockIdx.x & 31;   // col chunk (16 cols per gate)
  const int r0 = rt * 64 + wave * 16;
  const int col = cc * 16 + l15;
  const int bytemode = (int)(*flag);
  const float bhn_c = bhn[col];

  // weight-stationary B fragments: [gate][k-step]
  short8 bw[3][16];
#pragma unroll
  for (int kc = 0; kc < 16; ++kc)
#pragma unroll
    for (int g = 0; g < 3; ++g) {
      size_t u = (size_t)(kc * 4 + quad) * 1536 + (g * 512 + col);
      bw[g][kc] = *(const short8*)(Whf + u * 8);
    }

  const int myrowA = r0 + l15;
  const short8 z8 = {0, 0, 0, 0, 0, 0, 0, 0};

  for (int t = 0; t < TT; ++t) {
    if (t > 0) {
      if (tid == 0) {
        unsigned int* rp = &ready[rt * 130 + t];
        unsigned int v; long long guard = 0;
        do {
          v = __hip_atomic_load(rp, __ATOMIC_RELAXED, __HIP_MEMORY_SCOPE_AGENT);
        } while (v < 32u && ++guard < (1LL << 24));
        __builtin_amdgcn_fence(__ATOMIC_ACQUIRE, "agent");
      }
      __syncthreads();
    }
    const int par = t & 1;
    const unsigned short* hsrc = hbuf + (size_t)par * 262144;
    unsigned short* hdst = hbuf + (size_t)(par ^ 1) * 262144;

    // epilogue operands (issue early, consumed after MFMA)
    float ginr[4], ginz[4], ginn[4], hold[4];
    const unsigned short* gbase = gin + (size_t)(t * 512) * 1536;
#pragma unroll
    for (int i = 0; i < 4; ++i) {
      int row = r0 + quad * 4 + i;
      int dd = bytemode ? (int)dB[t * 512 + row] : dI[t * 512 + row];
      ginr[i] = bf2f(gbase[(size_t)row * 1536 + col]);
      ginz[i] = bf2f(gbase[(size_t)row * 1536 + 512 + col]);
      ginn[i] = bf2f(gbase[(size_t)row * 1536 + 1024 + col]);
      hold[i] = dd ? 0.f : bf2f(hsrc[(size_t)row * 512 + col]);
    }

    // A fragments: h rows (64B per row per k-step, fully coalesced per wave)
    int dA = bytemode ? (int)dB[t * 512 + myrowA] : dI[t * 512 + myrowA];
    const unsigned short* ap = hsrc + (size_t)myrowA * 512 + quad * 8;
    short8 af[16];
#pragma unroll
    for (int kc = 0; kc < 16; ++kc) af[kc] = *(const short8*)(ap + kc * 32);
    if (dA) {
#pragma unroll
      for (int kc = 0; kc < 16; ++kc) af[kc] = z8;
    }

    float4v a0 = {0.f, 0.f, 0.f, 0.f}, a1 = a0, a2 = a0;
#pragma unroll
    for (int kc = 0; kc < 16; ++kc) {
      a0 = __builtin_amdgcn_mfma_f32_16x16x32_bf16(af[kc], bw[0][kc], a0, 0, 0, 0);
      a1 = __builtin_amdgcn_mfma_f32_16x16x32_bf16(af[kc], bw[1][kc], a1, 0, 0, 0);
      a2 = __builtin_amdgcn_mfma_f32_16x16x32_bf16(af[kc], bw[2][kc], a2, 0, 0, 0);
    }

#pragma unroll
    for (int i = 0; i < 4; ++i) {
      int row = r0 + quad * 4 + i;
      float r = 1.f / (1.f + __expf(-(a0[i] + ginr[i])));
      float z = 1.f / (1.f + __expf(-(a1[i] + ginz[i])));
      float npre = ginn[i] + r * (a2[i] + bhn_c);
      float n = 1.f - 2.f / (1.f + __expf(2.f * npre));  // tanh, inf-safe
      float hnew = (1.f - z) * n + z * hold[i];
      unsigned short hb = f2bf(hnew);
      hdst[(size_t)row * 512 + col] = hb;
      ybuf[((size_t)(t * 512 + row)) * 512 + col] = hb;
      if (t == TT - 1) outh[(size_t)row * 512 + col] = hnew;
    }

    __syncthreads();  // drains all stores (vmcnt(0) before s_barrier)
    if (tid == 0)
      __hip_atomic_fetch_add(&ready[rt * 130 + t + 1], 1u, __ATOMIC_RELEASE,
                             __HIP_MEMORY_SCOPE_AGENT);
  }
}

// ---------------- phase C: q = y @ w_out + b_out (N padded to 64) -----------

__global__ __launch_bounds__(256) void k_qout(
    const unsigned short* __restrict__ Yb, const unsigned short* __restrict__ Wt,
    const float* __restrict__ bout, float* __restrict__ Q) {
  __shared__ unsigned short As[4096];
  __shared__ unsigned short Bs[2048];
  const int tid = threadIdx.x, wave = tid >> 6, lane = tid & 63;
  const int quad = lane >> 4, l15 = lane & 15;
  const int m0 = blockIdx.x * 128;

  float4v acc[2][4];
#pragma unroll
  for (int a = 0; a < 2; ++a)
#pragma unroll
    for (int b = 0; b < 4; ++b) acc[a][b] = (float4v){0.f, 0.f, 0.f, 0.f};

  for (int k0 = 0; k0 < 512; k0 += 32) {
#pragma unroll
    for (int r = 0; r < 2; ++r) {
      int u = r * 256 + wave * 64 + lane;
      int ch = u >> 7, mm = u & 127;
      async16(&As[(size_t)(r * 256 + wave * 64) * 8],
              Yb + (size_t)(m0 + mm) * 512 + k0 + ch * 8);
    }
    {
      int u = wave * 64 + lane;
      int ch = u >> 6, nn = u & 63;
      async16(&Bs[(size_t)(wave * 64) * 8], Wt + (size_t)nn * 512 + k0 + ch * 8);
    }
    __syncthreads();
    short8 afr[2], bfr[4];
#pragma unroll
    for (int mi = 0; mi < 2; ++mi)
      afr[mi] = *(const short8*)&As[((quad << 7) + wave * 32 + mi * 16 + l15) * 8];
#pragma unroll
    for (int ni = 0; ni < 4; ++ni)
      bfr[ni] = *(const short8*)&Bs[((quad << 6) + ni * 16 + l15) * 8];
#pragma unroll
    for (int mi = 0; mi < 2; ++mi)
#pragma unroll
      for (int ni = 0; ni < 4; ++ni)
        acc[mi][ni] = __builtin_amdgcn_mfma_f32_16x16x32_bf16(
            afr[mi], bfr[ni], acc[mi][ni], 0, 0, 0);
    __syncthreads();
  }
#pragma unroll
  for (int mi = 0; mi < 2; ++mi)
#pragma unroll
    for (int ni = 0; ni < 4; ++ni)
#pragma unroll
      for (int i = 0; i < 4; ++i) {
        int row = m0 + wave * 32 + mi * 16 + quad * 4 + i;
        int colq = ni * 16 + l15;
        if (colq < AD) Q[(size_t)row * AD + colq] = acc[mi][ni][i] + bout[colq];
      }
}

// ---------------- launch ----------------------------------------------------

extern "C" void kernel_launch(void* const* d_in, const int* in_sizes, int n_in,
                              void* d_out, int out_size, void* d_ws,
                              size_t ws_size, hipStream_t stream) {
  const float* hidden = (const float*)d_in[0];
  const float* obs = (const float*)d_in[1];
  const void* dones = d_in[2];
  const int* acts = (const int*)d_in[3];
  const float* w0 = (const float*)d_in[4];
  const float* b0 = (const float*)d_in[5];
  const float* ln0s = (const float*)d_in[6];
  const float* ln0b = (const float*)d_in[7];
  const float* w1 = (const float*)d_in[8];
  const float* b1 = (const float*)d_in[9];
  const float* ln1s = (const float*)d_in[10];
  const float* ln1b = (const float*)d_in[11];
  const float* wir = (const float*)d_in[12];
  const float* bir = (const float*)d_in[13];
  const float* wiz = (const float*)d_in[14];
  const float* biz = (const float*)d_in[15];
  const float* win = (const float*)d_in[16];
  const float* bin = (const float*)d_in[17];
  const float* whr = (const float*)d_in[18];
  const float* whz = (const float*)d_in[19];
  const float* whn = (const float*)d_in[20];
  const float* bhn = (const float*)d_in[21];
  const float* wout = (const float*)d_in[22];
  const float* bout = (const float*)d_in[23];

  char* ws = (char*)d_ws;
  unsigned short* bufA = (unsigned short*)(ws);                   // 64MB: obs_bf -> x1 -> x2
  unsigned short* bufB = (unsigned short*)(ws + 67108864ULL);     // 64MB: pre0 -> pre1 -> y
  unsigned short* gin = (unsigned short*)(ws + 134217728ULL);     // 192MB
  char* D = ws + 134217728ULL + 201326592ULL;
  unsigned short* W0at = (unsigned short*)(D);                    // 512KB
  unsigned short* W1t = (unsigned short*)(D + 524288);            // 512KB
  unsigned short* Wit = (unsigned short*)(D + 1048576);           // 1.5MB
  unsigned short* Whf = (unsigned short*)(D + 2621440);           // 1.5MB
  unsigned short* WoutT = (unsigned short*)(D + 4194304);         // 64KB
  unsigned short* w0act = (unsigned short*)(D + 4259840);         // 32KB
  float* gib = (float*)(D + 4292608);                             // 8KB
  unsigned short* hbuf = (unsigned short*)(D + 4300800);          // 1MB (2 parities)
  unsigned int* ready = (unsigned int*)(D + 5349376);             // counters
  unsigned int* flag = ready + 1040;

  (void)in_sizes; (void)n_in; (void)out_size; (void)ws_size;

  k_conv_obs<<<32768, 256, 0, stream>>>(obs, bufA, flag);
  k_prep_t<<<dim3(1024, 5), 256, 0, stream>>>(w0, w1, wir, wiz, win, W0at, W1t, Wit);
  k_prep_whf<<<3072, 256, 0, stream>>>(whr, whz, whn, Whf);
  k_prep_misc<<<1024, 256, 0, stream>>>(w0, bir, biz, bin, wout, hidden,
                                        (const int*)dones, w0act, gib, WoutT,
                                        hbuf, ready, flag);
  // encoder
  k_gemm_bt<1><<<dim3(512, 4), 256, 0, stream>>>(bufA, W0at, bufB, 512, b0, w0act, acts);
  k_ln_relu<<<16384, 256, 0, stream>>>(bufB, bufA, ln0s, ln0b);
  k_gemm_bt<0><<<dim3(512, 4), 256, 0, stream>>>(bufA, W1t, bufB, 512, b1, nullptr, nullptr);
  k_ln_relu<<<16384, 256, 0, stream>>>(bufB, bufA, ln1s, ln1b);
  // GRU input projections (biases fused)
  k_gemm_bt<0><<<dim3(512, 12), 256, 0, stream>>>(bufA, Wit, gin, 1536, gib, nullptr, nullptr);
  // sequential scan; writes new_hidden to d_out[0:262144] and y to bufB
  k_gru<<<256, 256, 0, stream>>>(Whf, gin, bhn, (const int*)dones,
                                 (const unsigned char*)dones, flag, hbuf, bufB,
                                 (float*)d_out, ready);
  // output head -> d_out[262144:]
  k_qout<<<512, 256, 0, stream>>>(bufB, WoutT, bout, (float*)d_out + 262144);
}

// Round 2
// 2278.688 us; speedup vs baseline: 1.1465x; 1.1465x over previous
//
#include <hip/hip_runtime.h>
#include <cstdint>
#include <cstddef>

// RNNQNetwork: MLP encoder (bf16 MFMA GEMMs) -> 128-step GRU scan
// (weight-stationary-in-VGPR distributed GEMM + per-row-group flag barriers)
// -> output head GEMM.
//
// R2 change: GRU barrier = per-producer flag STORES + 32-lane ballot poll
// (R1's single-counter atomic_fetch_add serialized 32 cross-XCD RMWs ~15us).
// Block mapping rt=blockIdx&7 so each row-group's 32 blocks share an XCD.

#define TT 128
#define BBATCH 512
#define HH 512
#define MM 65536   // T*B
#define AD 18

typedef __attribute__((ext_vector_type(8))) short short8;
typedef __attribute__((ext_vector_type(4))) float float4v;
typedef __attribute__((ext_vector_type(4))) unsigned int uint4v;

__device__ __forceinline__ unsigned short f2bf(float f) {
  union { float f; unsigned int u; } v; v.f = f;
  unsigned int r = v.u + 0x7fffu + ((v.u >> 16) & 1u);  // RNE
  return (unsigned short)(r >> 16);
}
__device__ __forceinline__ float bf2f(unsigned short h) {
  union { unsigned int u; float f; } v; v.u = ((unsigned int)h) << 16;
  return v.f;
}

// async global->LDS, 16B per lane. LDS dest must be wave-uniform base;
// lanes deposit at base + lane*16 (guide section 5 caveat).
typedef __attribute__((address_space(3))) unsigned int* lds_u32p;
typedef const __attribute__((address_space(1))) unsigned int* glb_u32p;
__device__ __forceinline__ void async16(void* lds, const void* g) {
  __builtin_amdgcn_global_load_lds(
      (glb_u32p)(unsigned long long)g,
      (lds_u32p)(unsigned int)(unsigned long long)lds, 16, 0, 0);
}

// ---------------- prep kernels ----------------

// obs fp32 -> bf16 (packed 4/thread); also zero the dones-format flag.
__global__ __launch_bounds__(256) void k_conv_obs(
    const float* __restrict__ src, unsigned short* __restrict__ dst,
    unsigned int* __restrict__ flag) {
  if (blockIdx.x == 0 && threadIdx.x == 0) *flag = 0u;
  int i = blockIdx.x * 256 + threadIdx.x;      // grid sized exactly
  float4v v = ((const float4v*)src)[i];
  unsigned long long pk = (unsigned long long)f2bf(v[0])
      | ((unsigned long long)f2bf(v[1]) << 16)
      | ((unsigned long long)f2bf(v[2]) << 32)
      | ((unsigned long long)f2bf(v[3]) << 48);
  ((unsigned long long*)dst)[i] = pk;
}

// Transpose [512][512] fp32 weights -> [N][K] bf16 (B^T layout for gemm_bt).
// z: 0=w0(first 512 rows), 1=w1, 2=w_ir, 3=w_iz, 4=w_in (into Wi_t slabs).
__global__ __launch_bounds__(256) void k_prep_t(
    const float* __restrict__ w0, const float* __restrict__ w1,
    const float* __restrict__ wir, const float* __restrict__ wiz,
    const float* __restrict__ win,
    unsigned short* __restrict__ W0at, unsigned short* __restrict__ W1t,
    unsigned short* __restrict__ Wit) {
  int o = blockIdx.x * 256 + threadIdx.x;  // o = n*512 + k
  int n = o >> 9, k = o & 511;
  int z = blockIdx.y;
  const float* s = (z == 0) ? w0 : (z == 1) ? w1 : (z == 2) ? wir
                 : (z == 3) ? wiz : win;
  unsigned short b = f2bf(s[k * 512 + n]);
  if (z == 0) W0at[o] = b;
  else if (z == 1) W1t[o] = b;
  else Wit[(size_t)(z - 2) * 262144 + o] = b;
}

// Hidden weights [w_hr|w_hz|w_hn] -> MFMA-B-fragment layout:
// Whf unit (k>>3)*1536 + n holds bf16 W[k0..k0+8][n] contiguously (16B).
__global__ __launch_bounds__(256) void k_prep_whf(
    const float* __restrict__ whr, const float* __restrict__ whz,
    const float* __restrict__ whn, unsigned short* __restrict__ Whf) {
  int i = blockIdx.x * 256 + threadIdx.x;  // < 512*1536, grid exact
  int k = i / 1536, n = i - k * 1536;
  const float* s = (n < 512) ? whr : (n < 1024) ? whz : whn;
  float v = s[k * 512 + (n & 511)];
  Whf[((size_t)(k >> 3) * 1536 + n) * 8 + (k & 7)] = f2bf(v);
}

// Misc: w0 action rows (bf16), combined gru-input bias, w_out^T padded to 64,
// initial h (bf16, parity 0), zero barrier flags, detect dones dtype.
__global__ __launch_bounds__(256) void k_prep_misc(
    const float* __restrict__ w0, const float* __restrict__ bir,
    const float* __restrict__ biz, const float* __restrict__ bin,
    const float* __restrict__ wout, const float* __restrict__ hidden,
    const int* __restrict__ dI,
    unsigned short* __restrict__ w0act, float* __restrict__ gib,
    unsigned short* __restrict__ WoutT, unsigned short* __restrict__ hbuf,
    unsigned int* __restrict__ ready, unsigned int* __restrict__ flag) {
  int i = blockIdx.x * 256 + threadIdx.x;  // grid 1024 -> i < 262144
  if (i < 9216) {
    int a = i >> 9, n = i & 511;
    w0act[i] = f2bf(w0[(512 + a) * 512 + n]);
  }
  if (i < 1536)
    gib[i] = (i < 512) ? bir[i] : (i < 1024) ? biz[i - 512] : bin[i - 1024];
  if (i < 32768) {
    int n = i >> 9, k = i & 511;
    WoutT[i] = f2bf(n < AD ? wout[k * AD + n] : 0.f);
  }
  if (i < 262144) hbuf[i] = f2bf(hidden[i]);
  if (i < 33280) ready[i] = 0u;  // 8 groups x 130 steps x 32 producers
  // dones dtype probe: first 64KB viewed as int32. int32 bools are only
  // {0,1}; packed byte-bools produce values with bits above bit0.
  if (i < 16384) { if (dI[i] & 0xFFFFFFFE) atomicOr(flag, 1u); }
}

// ---------------- phase A: GEMM C = A @ B^T (+bias [+one-hot gather]) ------

template <int MODE>  // MODE 1: add gathered w0 action row (GEMM1)
__global__ __launch_bounds__(256) void k_gemm_bt(
    const unsigned short* __restrict__ Ab,   // [M][512] bf16
    const unsigned short* __restrict__ Btb,  // [N][512] bf16
    unsigned short* __restrict__ Cb,         // [M][Ndim] bf16
    int Ndim, const float* __restrict__ bias,
    const unsigned short* __restrict__ gW,   // [18][512] bf16
    const int* __restrict__ acts) {
  // chunk-major LDS tiles: unit u = chunk*128 + row, 16B per unit (8 bf16 of k)
  __shared__ unsigned short As[4096];
  __shared__ unsigned short Bs[4096];
  const int tid = threadIdx.x, wave = tid >> 6, lane = tid & 63;
  const int quad = lane >> 4, l15 = lane & 15;
  const int m0 = blockIdx.x * 128, n0 = blockIdx.y * 128;
  const int mblk = (wave & 1) * 64, nblk = (wave >> 1) * 64;

  float4v acc[4][4];
#pragma unroll
  for (int a = 0; a < 4; ++a)
#pragma unroll
    for (int b = 0; b < 4; ++b) acc[a][b] = (float4v){0.f, 0.f, 0.f, 0.f};

  for (int k0 = 0; k0 < 512; k0 += 32) {
#pragma unroll
    for (int r = 0; r < 2; ++r) {
      int u = r * 256 + wave * 64 + lane;
      int ch = u >> 7, mm = u & 127;
      async16(&As[(size_t)(r * 256 + wave * 64) * 8],
              Ab + (size_t)(m0 + mm) * 512 + k0 + ch * 8);
      async16(&Bs[(size_t)(r * 256 + wave * 64) * 8],
              Btb + (size_t)(n0 + mm) * 512 + k0 + ch * 8);
    }
    __syncthreads();  // compiler drains vmcnt before s_barrier
    short8 afr[4], bfr[4];
#pragma unroll
    for (int mi = 0; mi < 4; ++mi)
      afr[mi] = *(const short8*)&As[((quad << 7) + mblk + mi * 16 + l15) * 8];
#pragma unroll
    for (int ni = 0; ni < 4; ++ni)
      bfr[ni] = *(const short8*)&Bs[((quad << 7) + nblk + ni * 16 + l15) * 8];
#pragma unroll
    for (int mi = 0; mi < 4; ++mi)
#pragma unroll
      for (int ni = 0; ni < 4; ++ni)
        acc[mi][ni] = __builtin_amdgcn_mfma_f32_16x16x32_bf16(
            afr[mi], bfr[ni], acc[mi][ni], 0, 0, 0);
    __syncthreads();
  }

#pragma unroll
  for (int mi = 0; mi < 4; ++mi) {
#pragma unroll
    for (int i = 0; i < 4; ++i) {
      int row = m0 + mblk + mi * 16 + quad * 4 + i;
      int arow = (MODE == 1) ? acts[row] : 0;
#pragma unroll
      for (int ni = 0; ni < 4; ++ni) {
        int col = n0 + nblk + ni * 16 + l15;
        float v = acc[mi][ni][i] + bias[col];
        if (MODE == 1) v += bf2f(gW[arow * 512 + col]);
        Cb[(size_t)row * Ndim + col] = f2bf(v);
      }
    }
  }
}

// ---------------- LayerNorm(+bias already applied) + ReLU, bf16->bf16 -------

__global__ __launch_bounds__(256) void k_ln_relu(
    const unsigned short* __restrict__ X, unsigned short* __restrict__ Y,
    const float* __restrict__ sc, const float* __restrict__ bi) {
  int row = blockIdx.x * 4 + (threadIdx.x >> 6);  // one wave per row
  int lane = threadIdx.x & 63;
  uint4v u = *(const uint4v*)(X + (size_t)row * 512 + lane * 8);
  float v[8];
#pragma unroll
  for (int j = 0; j < 4; ++j) {
    v[2 * j] = bf2f((unsigned short)(u[j] & 0xffffu));
    v[2 * j + 1] = bf2f((unsigned short)(u[j] >> 16));
  }
  float s = 0.f, q = 0.f;
#pragma unroll
  for (int j = 0; j < 8; ++j) { s += v[j]; q += v[j] * v[j]; }
#pragma unroll
  for (int d = 1; d < 64; d <<= 1) {
    s += __shfl_xor(s, d, 64);
    q += __shfl_xor(q, d, 64);
  }
  float mean = s * (1.f / 512.f);
  float var = fmaxf(q * (1.f / 512.f) - mean * mean, 0.f);
  float rstd = rsqrtf(var + 1e-6f);
  float4v s0 = *(const float4v*)(sc + lane * 8);
  float4v s1 = *(const float4v*)(sc + lane * 8 + 4);
  float4v c0 = *(const float4v*)(bi + lane * 8);
  float4v c1 = *(const float4v*)(bi + lane * 8 + 4);
  uint4v w;
#pragma unroll
  for (int j = 0; j < 4; ++j) {
    float a0 = fmaxf((v[2 * j] - mean) * rstd * (j < 2 ? s0[2 * j] : s1[2 * j - 4])
                         + (j < 2 ? c0[2 * j] : c1[2 * j - 4]), 0.f);
    float a1 = fmaxf((v[2 * j + 1] - mean) * rstd
                         * (j < 2 ? s0[2 * j + 1] : s1[2 * j - 3])
                         + (j < 2 ? c0[2 * j + 1] : c1[2 * j - 3]), 0.f);
    w[j] = (unsigned int)f2bf(a0) | ((unsigned int)f2bf(a1) << 16);
  }
  *(uint4v*)(Y + (size_t)row * 512 + lane * 8) = w;
}

// ---------------- phase B: GRU scan -----------------------------------------
// 256 blocks (8 row-groups x 32 col-chunks) x 256 threads, all co-resident by
// capacity (1 block/CU). Each wave: 16 h-rows x 16 cols x 3 gates.
// Hidden weights live in VGPRs (~48 VGPR/lane) for the whole scan.
// Mapping rt=blockIdx&7: under round-robin blockIdx->XCD dispatch all 32
// blocks of a row group share one XCD (speed heuristic only).
// Barrier: each producer release-STORES its own flag (no RMW contention);
// consumer wave polls 32 flags in parallel with ballot, then agent acquire
// fence (handles cross-XCD L2 non-coherence if placement differs).

__global__ __launch_bounds__(256, 1) void k_gru(
    const unsigned short* __restrict__ Whf, const unsigned short* __restrict__ gin,
    const float* __restrict__ bhn, const int* __restrict__ dI,
    const unsigned char* __restrict__ dB, const unsigned int* __restrict__ flag,
    unsigned short* __restrict__ hbuf, unsigned short* __restrict__ ybuf,
    float* __restrict__ outh, unsigned int* __restrict__ ready) {
  const int tid = threadIdx.x, wave = tid >> 6, lane = tid & 63;
  const int quad = lane >> 4, l15 = lane & 15;
  const int rt = blockIdx.x & 7;    // row group (64 rows) == XCD under RR
  const int cc = blockIdx.x >> 3;   // col chunk (16 cols per gate), 0..31
  const int r0 = rt * 64 + wave * 16;
  const int col = cc * 16 + l15;
  const int bytemode = (int)(*flag);
  const float bhn_c = bhn[col];

  // weight-stationary B fragments: [gate][k-step]
  short8 bw[3][16];
#pragma unroll
  for (int kc = 0; kc < 16; ++kc)
#pragma unroll
    for (int g = 0; g < 3; ++g) {
      size_t u = (size_t)(kc * 4 + quad) * 1536 + (g * 512 + col);
      bw[g][kc] = *(const short8*)(Whf + u * 8);
    }

  const int myrowA = r0 + l15;
  const short8 z8 = {0, 0, 0, 0, 0, 0, 0, 0};

  for (int t = 0; t < TT; ++t) {
    if (t > 0) {
      if (wave == 0) {
        // 32 lanes poll 32 per-producer flags in parallel
        const unsigned int* fp =
            ready + ((size_t)rt * 130 + t) * 32 + (lane & 31);
        unsigned int v;
        int guard = 0;
        do {
          v = __hip_atomic_load(fp, __ATOMIC_RELAXED,
                                __HIP_MEMORY_SCOPE_AGENT);
        } while (__ballot(v == 0u) != 0ull && ++guard < (1 << 24));
        __builtin_amdgcn_fence(__ATOMIC_ACQUIRE, "agent");
      }
      __syncthreads();
    }
    const int par = t & 1;
    const unsigned short* hsrc = hbuf + (size_t)par * 262144;
    unsigned short* hdst = hbuf + (size_t)(par ^ 1) * 262144;

    // epilogue operands (issue early, consumed after MFMA)
    float ginr[4], ginz[4], ginn[4], hold[4];
    const unsigned short* gbase = gin + (size_t)(t * 512) * 1536;
#pragma unroll
    for (int i = 0; i < 4; ++i) {
      int row = r0 + quad * 4 + i;
      int dd = bytemode ? (int)dB[t * 512 + row] : dI[t * 512 + row];
      ginr[i] = bf2f(gbase[(size_t)row * 1536 + col]);
      ginz[i] = bf2f(gbase[(size_t)row * 1536 + 512 + col]);
      ginn[i] = bf2f(gbase[(size_t)row * 1536 + 1024 + col]);
      hold[i] = dd ? 0.f : bf2f(hsrc[(size_t)row * 512 + col]);
    }

    // A fragments: h rows (64B per row per k-step, fully coalesced per wave)
    int dA = bytemode ? (int)dB[t * 512 + myrowA] : dI[t * 512 + myrowA];
    const unsigned short* ap = hsrc + (size_t)myrowA * 512 + quad * 8;
    short8 af[16];
#pragma unroll
    for (int kc = 0; kc < 16; ++kc) af[kc] = *(const short8*)(ap + kc * 32);
    if (dA) {
#pragma unroll
      for (int kc = 0; kc < 16; ++kc) af[kc] = z8;
    }

    float4v a0 = {0.f, 0.f, 0.f, 0.f}, a1 = a0, a2 = a0;
#pragma unroll
    for (int kc = 0; kc < 16; ++kc) {
      a0 = __builtin_amdgcn_mfma_f32_16x16x32_bf16(af[kc], bw[0][kc], a0, 0, 0, 0);
      a1 = __builtin_amdgcn_mfma_f32_16x16x32_bf16(af[kc], bw[1][kc], a1, 0, 0, 0);
      a2 = __builtin_amdgcn_mfma_f32_16x16x32_bf16(af[kc], bw[2][kc], a2, 0, 0, 0);
    }

#pragma unroll
    for (int i = 0; i < 4; ++i) {
      int row = r0 + quad * 4 + i;
      float r = 1.f / (1.f + __expf(-(a0[i] + ginr[i])));
      float z = 1.f / (1.f + __expf(-(a1[i] + ginz[i])));
      float npre = ginn[i] + r * (a2[i] + bhn_c);
      float n = 1.f - 2.f / (1.f + __expf(2.f * npre));  // tanh, inf-safe
      float hnew = (1.f - z) * n + z * hold[i];
      unsigned short hb = f2bf(hnew);
      hdst[(size_t)row * 512 + col] = hb;
      ybuf[((size_t)(t * 512 + row)) * 512 + col] = hb;
      if (t == TT - 1) outh[(size_t)row * 512 + col] = hnew;
    }

    __syncthreads();  // drains all stores (vmcnt(0) before s_barrier)
    if (tid == 0)
      __hip_atomic_store(&ready[((size_t)rt * 130 + t + 1) * 32 + cc], 1u,
                         __ATOMIC_RELEASE, __HIP_MEMORY_SCOPE_AGENT);
  }
}

// ---------------- phase C: q = y @ w_out + b_out (N padded to 64) -----------

__global__ __launch_bounds__(256) void k_qout(
    const unsigned short* __restrict__ Yb, const unsigned short* __restrict__ Wt,
    const float* __restrict__ bout, float* __restrict__ Q) {
  __shared__ unsigned short As[4096];
  __shared__ unsigned short Bs[2048];
  const int tid = threadIdx.x, wave = tid >> 6, lane = tid & 63;
  const int quad = lane >> 4, l15 = lane & 15;
  const int m0 = blockIdx.x * 128;

  float4v acc[2][4];
#pragma unroll
  for (int a = 0; a < 2; ++a)
#pragma unroll
    for (int b = 0; b < 4; ++b) acc[a][b] = (float4v){0.f, 0.f, 0.f, 0.f};

  for (int k0 = 0; k0 < 512; k0 += 32) {
#pragma unroll
    for (int r = 0; r < 2; ++r) {
      int u = r * 256 + wave * 64 + lane;
      int ch = u >> 7, mm = u & 127;
      async16(&As[(size_t)(r * 256 + wave * 64) * 8],
              Yb + (size_t)(m0 + mm) * 512 + k0 + ch * 8);
    }
    {
      int u = wave * 64 + lane;
      int ch = u >> 6, nn = u & 63;
      async16(&Bs[(size_t)(wave * 64) * 8], Wt + (size_t)nn * 512 + k0 + ch * 8);
    }
    __syncthreads();
    short8 afr[2], bfr[4];
#pragma unroll
    for (int mi = 0; mi < 2; ++mi)
      afr[mi] = *(const short8*)&As[((quad << 7) + wave * 32 + mi * 16 + l15) * 8];
#pragma unroll
    for (int ni = 0; ni < 4; ++ni)
      bfr[ni] = *(const short8*)&Bs[((quad << 6) + ni * 16 + l15) * 8];
#pragma unroll
    for (int mi = 0; mi < 2; ++mi)
#pragma unroll
      for (int ni = 0; ni < 4; ++ni)
        acc[mi][ni] = __builtin_amdgcn_mfma_f32_16x16x32_bf16(
            afr[mi], bfr[ni], acc[mi][ni], 0, 0, 0);
    __syncthreads();
  }
#pragma unroll
  for (int mi = 0; mi < 2; ++mi)
#pragma unroll
    for (int ni = 0; ni < 4; ++ni)
#pragma unroll
      for (int i = 0; i < 4; ++i) {
        int row = m0 + wave * 32 + mi * 16 + quad * 4 + i;
        int colq = ni * 16 + l15;
        if (colq < AD) Q[(size_t)row * AD + colq] = acc[mi][ni][i] + bout[colq];
      }
}

// ---------------- launch ----------------------------------------------------

extern "C" void kernel_launch(void* const* d_in, const int* in_sizes, int n_in,
                              void* d_out, int out_size, void* d_ws,
                              size_t ws_size, hipStream_t stream) {
  const float* hidden = (const float*)d_in[0];
  const float* obs = (const float*)d_in[1];
  const void* dones = d_in[2];
  const int* acts = (const int*)d_in[3];
  const float* w0 = (const float*)d_in[4];
  const float* b0 = (const float*)d_in[5];
  const float* ln0s = (const float*)d_in[6];
  const float* ln0b = (const float*)d_in[7];
  const float* w1 = (const float*)d_in[8];
  const float* b1 = (const float*)d_in[9];
  const float* ln1s = (const float*)d_in[10];
  const float* ln1b = (const float*)d_in[11];
  const float* wir = (const float*)d_in[12];
  const float* bir = (const float*)d_in[13];
  const float* wiz = (const float*)d_in[14];
  const float* biz = (const float*)d_in[15];
  const float* win = (const float*)d_in[16];
  const float* bin = (const float*)d_in[17];
  const float* whr = (const float*)d_in[18];
  const float* whz = (const float*)d_in[19];
  const float* whn = (const float*)d_in[20];
  const float* bhn = (const float*)d_in[21];
  const float* wout = (const float*)d_in[22];
  const float* bout = (const float*)d_in[23];

  char* ws = (char*)d_ws;
  unsigned short* bufA = (unsigned short*)(ws);                   // 64MB: obs_bf -> x1 -> x2
  unsigned short* bufB = (unsigned short*)(ws + 67108864ULL);     // 64MB: pre0 -> pre1 -> y
  unsigned short* gin = (unsigned short*)(ws + 134217728ULL);     // 192MB
  char* D = ws + 134217728ULL + 201326592ULL;
  unsigned short* W0at = (unsigned short*)(D);                    // 512KB
  unsigned short* W1t = (unsigned short*)(D + 524288);            // 512KB
  unsigned short* Wit = (unsigned short*)(D + 1048576);           // 1.5MB
  unsigned short* Whf = (unsigned short*)(D + 2621440);           // 1.5MB
  unsigned short* WoutT = (unsigned short*)(D + 4194304);         // 64KB
  unsigned short* w0act = (unsigned short*)(D + 4259840);         // 32KB
  float* gib = (float*)(D + 4292608);                             // 8KB
  unsigned short* hbuf = (unsigned short*)(D + 4300800);          // 1MB (2 parities)
  unsigned int* ready = (unsigned int*)(D + 5349376);             // 133KB flags
  unsigned int* flag = ready + 33280;

  (void)in_sizes; (void)n_in; (void)out_size; (void)ws_size;

  k_conv_obs<<<32768, 256, 0, stream>>>(obs, bufA, flag);
  k_prep_t<<<dim3(1024, 5), 256, 0, stream>>>(w0, w1, wir, wiz, win, W0at, W1t, Wit);
  k_prep_whf<<<3072, 256, 0, stream>>>(whr, whz, whn, Whf);
  k_prep_misc<<<1024, 256, 0, stream>>>(w0, bir, biz, bin, wout, hidden,
                                        (const int*)dones, w0act, gib, WoutT,
                                        hbuf, ready, flag);
  // encoder
  k_gemm_bt<1><<<dim3(512, 4), 256, 0, stream>>>(bufA, W0at, bufB, 512, b0, w0act, acts);
  k_ln_relu<<<16384, 256, 0, stream>>>(bufB, bufA, ln0s, ln0b);
  k_gemm_bt<0><<<dim3(512, 4), 256, 0, stream>>>(bufA, W1t, bufB, 512, b1, nullptr, nullptr);
  k_ln_relu<<<16384, 256, 0, stream>>>(bufB, bufA, ln1s, ln1b);
  // GRU input projections (biases fused)
  k_gemm_bt<0><<<dim3(512, 12), 256, 0, stream>>>(bufA, Wit, gin, 1536, gib, nullptr, nullptr);
  // sequential scan; writes new_hidden to d_out[0:262144] and y to bufB
  k_gru<<<256, 256, 0, stream>>>(Whf, gin, bhn, (const int*)dones,
                                 (const unsigned char*)dones, flag, hbuf, bufB,
                                 (float*)d_out, ready);
  // output head -> d_out[262144:]
  k_qout<<<512, 256, 0, stream>>>(bufB, WoutT, bout, (float*)d_out + 262144);
}

// Round 4
// 1361.229 us; speedup vs baseline: 1.9193x; 1.6740x over previous
//
#include <hip/hip_runtime.h>
#include <cstdint>
#include <cstddef>

// RNNQNetwork: MLP encoder (bf16 MFMA GEMMs) -> 128-step GRU scan
// (weight-stationary distributed GEMM, cross-block handoff via per-access
// coherent sc0/sc1 ops + per-step fresh h buffer) -> output head GEMM.
//
// R4: R3's nontemporal handoff raced (nt = LRU hint only, NOT cache bypass
// on gfx950). Correct per-access coherence is sc0 sc1 (what device-scope
// atomics compile to; no buffer_wbl2/buffer_inv, unlike fences - R2's 12us/
// step cost). Flags: sc0sc1 loads/stores. h: producer write-through sc0sc1
// shorts into ybuf[t] (fresh region per step), drained by __syncthreads'
// vmcnt(0) before flag publish; consumer reads ybuf[t-1] with NORMAL cached
// loads (addresses never touched before within k_gru => no stale lines;
// same-XCD blocks share the L2 fill). gin/dones prefetched one step ahead.

#define TT 128
#define BBATCH 512
#define HH 512
#define MM 65536   // T*B
#define AD 18

typedef __attribute__((ext_vector_type(8))) short short8;
typedef __attribute__((ext_vector_type(4))) float float4v;
typedef __attribute__((ext_vector_type(4))) unsigned int uint4v;

__device__ __forceinline__ unsigned short f2bf(float f) {
  union { float f; unsigned int u; } v; v.f = f;
  unsigned int r = v.u + 0x7fffu + ((v.u >> 16) & 1u);  // RNE
  return (unsigned short)(r >> 16);
}
__device__ __forceinline__ float bf2f(unsigned short h) {
  union { unsigned int u; float f; } v; v.u = ((unsigned int)h) << 16;
  return v.f;
}

// per-access coherent (coherence-point) ops: sc0 sc1 = device-scope, no fence
__device__ __forceinline__ unsigned int load_u32_coh(const unsigned int* p) {
  unsigned int v;
  asm volatile("global_load_dword %0, %1, off sc0 sc1\n\ts_waitcnt vmcnt(0)"
               : "=v"(v) : "v"(p) : "memory");
  return v;
}
__device__ __forceinline__ void store_u32_coh(unsigned int* p, unsigned int v) {
  asm volatile("global_store_dword %0, %1, off sc0 sc1"
               :: "v"(p), "v"(v) : "memory");
}
__device__ __forceinline__ void store_u16_coh(unsigned short* p, unsigned int v) {
  asm volatile("global_store_short %0, %1, off sc0 sc1"
               :: "v"(p), "v"(v) : "memory");
}

// async global->LDS, 16B per lane. LDS dest must be wave-uniform base;
// lanes deposit at base + lane*16 (guide section 5 caveat).
typedef __attribute__((address_space(3))) unsigned int* lds_u32p;
typedef const __attribute__((address_space(1))) unsigned int* glb_u32p;
__device__ __forceinline__ void async16(void* lds, const void* g) {
  __builtin_amdgcn_global_load_lds(
      (glb_u32p)(unsigned long long)g,
      (lds_u32p)(unsigned int)(unsigned long long)lds, 16, 0, 0);
}

// ---------------- prep kernels ----------------

// obs fp32 -> bf16 (packed 4/thread); also zero the dones-format flag.
__global__ __launch_bounds__(256) void k_conv_obs(
    const float* __restrict__ src, unsigned short* __restrict__ dst,
    unsigned int* __restrict__ flag) {
  if (blockIdx.x == 0 && threadIdx.x == 0) *flag = 0u;
  int i = blockIdx.x * 256 + threadIdx.x;      // grid sized exactly
  float4v v = ((const float4v*)src)[i];
  unsigned long long pk = (unsigned long long)f2bf(v[0])
      | ((unsigned long long)f2bf(v[1]) << 16)
      | ((unsigned long long)f2bf(v[2]) << 32)
      | ((unsigned long long)f2bf(v[3]) << 48);
  ((unsigned long long*)dst)[i] = pk;
}

// Transpose [512][512] fp32 weights -> [N][K] bf16 (B^T layout for gemm_bt).
// z: 0=w0(first 512 rows), 1=w1, 2=w_ir, 3=w_iz, 4=w_in (into Wi_t slabs).
__global__ __launch_bounds__(256) void k_prep_t(
    const float* __restrict__ w0, const float* __restrict__ w1,
    const float* __restrict__ wir, const float* __restrict__ wiz,
    const float* __restrict__ win,
    unsigned short* __restrict__ W0at, unsigned short* __restrict__ W1t,
    unsigned short* __restrict__ Wit) {
  int o = blockIdx.x * 256 + threadIdx.x;  // o = n*512 + k
  int n = o >> 9, k = o & 511;
  int z = blockIdx.y;
  const float* s = (z == 0) ? w0 : (z == 1) ? w1 : (z == 2) ? wir
                 : (z == 3) ? wiz : win;
  unsigned short b = f2bf(s[k * 512 + n]);
  if (z == 0) W0at[o] = b;
  else if (z == 1) W1t[o] = b;
  else Wit[(size_t)(z - 2) * 262144 + o] = b;
}

// Hidden weights [w_hr|w_hz|w_hn] -> MFMA-B-fragment layout:
// Whf unit (k>>3)*1536 + n holds bf16 W[k0..k0+8][n] contiguously (16B).
__global__ __launch_bounds__(256) void k_prep_whf(
    const float* __restrict__ whr, const float* __restrict__ whz,
    const float* __restrict__ whn, unsigned short* __restrict__ Whf) {
  int i = blockIdx.x * 256 + threadIdx.x;  // < 512*1536, grid exact
  int k = i / 1536, n = i - k * 1536;
  const float* s = (n < 512) ? whr : (n < 1024) ? whz : whn;
  float v = s[k * 512 + (n & 511)];
  Whf[((size_t)(k >> 3) * 1536 + n) * 8 + (k & 7)] = f2bf(v);
}

// Misc: w0 action rows (bf16), combined gru-input bias, w_out^T padded to 64,
// initial h (bf16), zero barrier flags, detect dones dtype.
__global__ __launch_bounds__(256) void k_prep_misc(
    const float* __restrict__ w0, const float* __restrict__ bir,
    const float* __restrict__ biz, const float* __restrict__ bin,
    const float* __restrict__ wout, const float* __restrict__ hidden,
    const int* __restrict__ dI,
    unsigned short* __restrict__ w0act, float* __restrict__ gib,
    unsigned short* __restrict__ WoutT, unsigned short* __restrict__ hbuf,
    unsigned int* __restrict__ ready, unsigned int* __restrict__ flag) {
  int i = blockIdx.x * 256 + threadIdx.x;  // grid 1024 -> i < 262144
  if (i < 9216) {
    int a = i >> 9, n = i & 511;
    w0act[i] = f2bf(w0[(512 + a) * 512 + n]);
  }
  if (i < 1536)
    gib[i] = (i < 512) ? bir[i] : (i < 1024) ? biz[i - 512] : bin[i - 1024];
  if (i < 32768) {
    int n = i >> 9, k = i & 511;
    WoutT[i] = f2bf(n < AD ? wout[k * AD + n] : 0.f);
  }
  if (i < 262144) hbuf[i] = f2bf(hidden[i]);
  if (i < 33280) ready[i] = 0u;  // 8 groups x 130 steps x 32 producers
  // dones dtype probe: first 64KB viewed as int32. int32 bools are only
  // {0,1}; packed byte-bools produce values with bits above bit0.
  if (i < 16384) { if (dI[i] & 0xFFFFFFFE) atomicOr(flag, 1u); }
}

// ---------------- phase A: GEMM C = A @ B^T (+bias [+one-hot gather]) ------

template <int MODE>  // MODE 1: add gathered w0 action row (GEMM1)
__global__ __launch_bounds__(256) void k_gemm_bt(
    const unsigned short* __restrict__ Ab,   // [M][512] bf16
    const unsigned short* __restrict__ Btb,  // [N][512] bf16
    unsigned short* __restrict__ Cb,         // [M][Ndim] bf16
    int Ndim, const float* __restrict__ bias,
    const unsigned short* __restrict__ gW,   // [18][512] bf16
    const int* __restrict__ acts) {
  // chunk-major LDS tiles: unit u = chunk*128 + row, 16B per unit (8 bf16 of k)
  __shared__ unsigned short As[4096];
  __shared__ unsigned short Bs[4096];
  const int tid = threadIdx.x, wave = tid >> 6, lane = tid & 63;
  const int quad = lane >> 4, l15 = lane & 15;
  const int m0 = blockIdx.x * 128, n0 = blockIdx.y * 128;
  const int mblk = (wave & 1) * 64, nblk = (wave >> 1) * 64;

  float4v acc[4][4];
#pragma unroll
  for (int a = 0; a < 4; ++a)
#pragma unroll
    for (int b = 0; b < 4; ++b) acc[a][b] = (float4v){0.f, 0.f, 0.f, 0.f};

  for (int k0 = 0; k0 < 512; k0 += 32) {
#pragma unroll
    for (int r = 0; r < 2; ++r) {
      int u = r * 256 + wave * 64 + lane;
      int ch = u >> 7, mm = u & 127;
      async16(&As[(size_t)(r * 256 + wave * 64) * 8],
              Ab + (size_t)(m0 + mm) * 512 + k0 + ch * 8);
      async16(&Bs[(size_t)(r * 256 + wave * 64) * 8],
              Btb + (size_t)(n0 + mm) * 512 + k0 + ch * 8);
    }
    __syncthreads();  // compiler drains vmcnt before s_barrier
    short8 afr[4], bfr[4];
#pragma unroll
    for (int mi = 0; mi < 4; ++mi)
      afr[mi] = *(const short8*)&As[((quad << 7) + mblk + mi * 16 + l15) * 8];
#pragma unroll
    for (int ni = 0; ni < 4; ++ni)
      bfr[ni] = *(const short8*)&Bs[((quad << 7) + nblk + ni * 16 + l15) * 8];
#pragma unroll
    for (int mi = 0; mi < 4; ++mi)
#pragma unroll
      for (int ni = 0; ni < 4; ++ni)
        acc[mi][ni] = __builtin_amdgcn_mfma_f32_16x16x32_bf16(
            afr[mi], bfr[ni], acc[mi][ni], 0, 0, 0);
    __syncthreads();
  }

#pragma unroll
  for (int mi = 0; mi < 4; ++mi) {
#pragma unroll
    for (int i = 0; i < 4; ++i) {
      int row = m0 + mblk + mi * 16 + quad * 4 + i;
      int arow = (MODE == 1) ? acts[row] : 0;
#pragma unroll
      for (int ni = 0; ni < 4; ++ni) {
        int col = n0 + nblk + ni * 16 + l15;
        float v = acc[mi][ni][i] + bias[col];
        if (MODE == 1) v += bf2f(gW[arow * 512 + col]);
        Cb[(size_t)row * Ndim + col] = f2bf(v);
      }
    }
  }
}

// ---------------- LayerNorm(+bias already applied) + ReLU, bf16->bf16 -------

__global__ __launch_bounds__(256) void k_ln_relu(
    const unsigned short* __restrict__ X, unsigned short* __restrict__ Y,
    const float* __restrict__ sc, const float* __restrict__ bi) {
  int row = blockIdx.x * 4 + (threadIdx.x >> 6);  // one wave per row
  int lane = threadIdx.x & 63;
  uint4v u = *(const uint4v*)(X + (size_t)row * 512 + lane * 8);
  float v[8];
#pragma unroll
  for (int j = 0; j < 4; ++j) {
    v[2 * j] = bf2f((unsigned short)(u[j] & 0xffffu));
    v[2 * j + 1] = bf2f((unsigned short)(u[j] >> 16));
  }
  float s = 0.f, q = 0.f;
#pragma unroll
  for (int j = 0; j < 8; ++j) { s += v[j]; q += v[j] * v[j]; }
#pragma unroll
  for (int d = 1; d < 64; d <<= 1) {
    s += __shfl_xor(s, d, 64);
    q += __shfl_xor(q, d, 64);
  }
  float mean = s * (1.f / 512.f);
  float var = fmaxf(q * (1.f / 512.f) - mean * mean, 0.f);
  float rstd = rsqrtf(var + 1e-6f);
  float4v s0 = *(const float4v*)(sc + lane * 8);
  float4v s1 = *(const float4v*)(sc + lane * 8 + 4);
  float4v c0 = *(const float4v*)(bi + lane * 8);
  float4v c1 = *(const float4v*)(bi + lane * 8 + 4);
  uint4v w;
#pragma unroll
  for (int j = 0; j < 4; ++j) {
    float a0 = fmaxf((v[2 * j] - mean) * rstd * (j < 2 ? s0[2 * j] : s1[2 * j - 4])
                         + (j < 2 ? c0[2 * j] : c1[2 * j - 4]), 0.f);
    float a1 = fmaxf((v[2 * j + 1] - mean) * rstd
                         * (j < 2 ? s0[2 * j + 1] : s1[2 * j - 3])
                         + (j < 2 ? c0[2 * j + 1] : c1[2 * j - 3]), 0.f);
    w[j] = (unsigned int)f2bf(a0) | ((unsigned int)f2bf(a1) << 16);
  }
  *(uint4v*)(Y + (size_t)row * 512 + lane * 8) = w;
}

// ---------------- phase B: GRU scan -----------------------------------------
// 256 blocks (8 row-groups x 32 col-chunks) x 256 threads, 1 block/CU.
// Each wave: 16 h-rows x 16 cols x 3 gates; hidden weights weight-stationary.
// h history lives in ybuf[t] (= y output): producer write-through sc0sc1
// shorts, __syncthreads drains vmcnt(0), then per-producer flag store (sc0
// sc1). Consumer polls flags with sc0sc1 loads (never cached -> no stale-0
// deadlock), then reads ybuf[t-1] with NORMAL cached loads - that region is
// first-touched at this step, so no stale lines; same-XCD blocks (swizzle
// rt=blockIdx&7) share the L2 fill. gin/dones prefetched one step ahead.

__global__ __launch_bounds__(256, 1) void k_gru(
    const unsigned short* __restrict__ Whf, const unsigned short* __restrict__ gin,
    const float* __restrict__ bhn, const int* __restrict__ dI,
    const unsigned char* __restrict__ dB, const unsigned int* __restrict__ flag,
    const unsigned short* __restrict__ hbuf, unsigned short* __restrict__ ybuf,
    float* __restrict__ outh, unsigned int* __restrict__ ready) {
  const int tid = threadIdx.x, wave = tid >> 6, lane = tid & 63;
  const int quad = lane >> 4, l15 = lane & 15;
  const int rt = blockIdx.x & 7;    // row group (64 rows) == XCD under RR
  const int cc = blockIdx.x >> 3;   // col chunk (16 cols per gate), 0..31
  const int r0 = rt * 64 + wave * 16;
  const int col = cc * 16 + l15;
  const int bytemode = (int)(*flag);
  const float bhn_c = bhn[col];

  // weight-stationary B fragments: [gate][k-step]
  short8 bw[3][16];
#pragma unroll
  for (int kc = 0; kc < 16; ++kc)
#pragma unroll
    for (int g = 0; g < 3; ++g) {
      size_t u = (size_t)(kc * 4 + quad) * 1536 + (g * 512 + col);
      bw[g][kc] = *(const short8*)(Whf + u * 8);
    }

  // own h carried in registers (fp32) across steps
  float hprev[4];
#pragma unroll
  for (int i = 0; i < 4; ++i) {
    int row = r0 + quad * 4 + i;
    hprev[i] = bf2f(hbuf[(size_t)row * 512 + col]);
  }

  const int myrowA = r0 + l15;

  // prefetched per-step operands (gin + dones), loaded one step ahead
  float ginr[4], ginz[4], ginn[4];
  int dd[4], dA;
  {
    const unsigned short* gbase = gin;
#pragma unroll
    for (int i = 0; i < 4; ++i) {
      int row = r0 + quad * 4 + i;
      dd[i] = bytemode ? (int)dB[row] : dI[row];
      ginr[i] = bf2f(gbase[(size_t)row * 1536 + col]);
      ginz[i] = bf2f(gbase[(size_t)row * 1536 + 512 + col]);
      ginn[i] = bf2f(gbase[(size_t)row * 1536 + 1024 + col]);
    }
    dA = bytemode ? (int)dB[myrowA] : dI[myrowA];
  }

  for (int t = 0; t < TT; ++t) {
    if (t > 0) {
      if (wave == 0) {
        // 32 lanes poll 32 per-producer flags in parallel (coherence-point)
        const unsigned int* fp =
            ready + ((size_t)rt * 130 + t) * 32 + (lane & 31);
        unsigned int v;
        int guard = 0;
        do {
          v = load_u32_coh(fp);
        } while (__ballot(v == 0u) != 0ull && ++guard < (1 << 22));
      }
      __syncthreads();
      asm volatile("" ::: "memory");  // no hoisting h loads above the wait
    }

    // A fragments: h rows, normal cached loads from per-step-fresh region
    const unsigned short* hsrc =
        (t == 0) ? hbuf : ybuf + (size_t)(t - 1) * 262144;
    const unsigned short* ap = hsrc + (size_t)myrowA * 512 + quad * 8;
    short8 af[16];
#pragma unroll
    for (int kc = 0; kc < 16; ++kc) af[kc] = *(const short8*)(ap + kc * 32);
    if (dA) {
      const short8 z8 = {0, 0, 0, 0, 0, 0, 0, 0};
#pragma unroll
      for (int kc = 0; kc < 16; ++kc) af[kc] = z8;
    }

    float4v a0 = {0.f, 0.f, 0.f, 0.f}, a1 = a0, a2 = a0;
#pragma unroll
    for (int kc = 0; kc < 16; ++kc) {
      a0 = __builtin_amdgcn_mfma_f32_16x16x32_bf16(af[kc], bw[0][kc], a0, 0, 0, 0);
      a1 = __builtin_amdgcn_mfma_f32_16x16x32_bf16(af[kc], bw[1][kc], a1, 0, 0, 0);
      a2 = __builtin_amdgcn_mfma_f32_16x16x32_bf16(af[kc], bw[2][kc], a2, 0, 0, 0);
    }

    unsigned short* ydst = ybuf + (size_t)t * 262144;
#pragma unroll
    for (int i = 0; i < 4; ++i) {
      int row = r0 + quad * 4 + i;
      float hold = dd[i] ? 0.f : hprev[i];
      float r = 1.f / (1.f + __expf(-(a0[i] + ginr[i])));
      float z = 1.f / (1.f + __expf(-(a1[i] + ginz[i])));
      float npre = ginn[i] + r * (a2[i] + bhn_c);
      float n = 1.f - 2.f / (1.f + __expf(2.f * npre));  // tanh, inf-safe
      float hnew = (1.f - z) * n + z * hold;
      hprev[i] = hnew;
      // write-through to coherence point (L3): next step's cross-XCD input
      store_u16_coh(ydst + (size_t)row * 512 + col, (unsigned int)f2bf(hnew));
      if (t == TT - 1) outh[(size_t)row * 512 + col] = hnew;
    }

    __syncthreads();  // s_waitcnt vmcnt(0) before s_barrier: h at L3
    if (tid == 0)
      store_u32_coh(&ready[((size_t)rt * 130 + t + 1) * 32 + cc], 1u);

    // prefetch next step's gin + dones (independent of flags/h)
    if (t < TT - 1) {
      int tn = t + 1;
      const unsigned short* gbase = gin + (size_t)tn * 512 * 1536;
#pragma unroll
      for (int i = 0; i < 4; ++i) {
        int row = r0 + quad * 4 + i;
        dd[i] = bytemode ? (int)dB[tn * 512 + row] : dI[tn * 512 + row];
        ginr[i] = bf2f(gbase[(size_t)row * 1536 + col]);
        ginz[i] = bf2f(gbase[(size_t)row * 1536 + 512 + col]);
        ginn[i] = bf2f(gbase[(size_t)row * 1536 + 1024 + col]);
      }
      dA = bytemode ? (int)dB[tn * 512 + myrowA] : dI[tn * 512 + myrowA];
    }
  }
}

// ---------------- phase C: q = y @ w_out + b_out (N padded to 64) -----------

__global__ __launch_bounds__(256) void k_qout(
    const unsigned short* __restrict__ Yb, const unsigned short* __restrict__ Wt,
    const float* __restrict__ bout, float* __restrict__ Q) {
  __shared__ unsigned short As[4096];
  __shared__ unsigned short Bs[2048];
  const int tid = threadIdx.x, wave = tid >> 6, lane = tid & 63;
  const int quad = lane >> 4, l15 = lane & 15;
  const int m0 = blockIdx.x * 128;

  float4v acc[2][4];
#pragma unroll
  for (int a = 0; a < 2; ++a)
#pragma unroll
    for (int b = 0; b < 4; ++b) acc[a][b] = (float4v){0.f, 0.f, 0.f, 0.f};

  for (int k0 = 0; k0 < 512; k0 += 32) {
#pragma unroll
    for (int r = 0; r < 2; ++r) {
      int u = r * 256 + wave * 64 + lane;
      int ch = u >> 7, mm = u & 127;
      async16(&As[(size_t)(r * 256 + wave * 64) * 8],
              Yb + (size_t)(m0 + mm) * 512 + k0 + ch * 8);
    }
    {
      int u = wave * 64 + lane;
      int ch = u >> 6, nn = u & 63;
      async16(&Bs[(size_t)(wave * 64) * 8], Wt + (size_t)nn * 512 + k0 + ch * 8);
    }
    __syncthreads();
    short8 afr[2], bfr[4];
#pragma unroll
    for (int mi = 0; mi < 2; ++mi)
      afr[mi] = *(const short8*)&As[((quad << 7) + wave * 32 + mi * 16 + l15) * 8];
#pragma unroll
    for (int ni = 0; ni < 4; ++ni)
      bfr[ni] = *(const short8*)&Bs[((quad << 6) + ni * 16 + l15) * 8];
#pragma unroll
    for (int mi = 0; mi < 2; ++mi)
#pragma unroll
      for (int ni = 0; ni < 4; ++ni)
        acc[mi][ni] = __builtin_amdgcn_mfma_f32_16x16x32_bf16(
            afr[mi], bfr[ni], acc[mi][ni], 0, 0, 0);
    __syncthreads();
  }
#pragma unroll
  for (int mi = 0; mi < 2; ++mi)
#pragma unroll
    for (int ni = 0; ni < 4; ++ni)
#pragma unroll
      for (int i = 0; i < 4; ++i) {
        int row = m0 + wave * 32 + mi * 16 + quad * 4 + i;
        int colq = ni * 16 + l15;
        if (colq < AD) Q[(size_t)row * AD + colq] = acc[mi][ni][i] + bout[colq];
      }
}

// ---------------- launch ----------------------------------------------------

extern "C" void kernel_launch(void* const* d_in, const int* in_sizes, int n_in,
                              void* d_out, int out_size, void* d_ws,
                              size_t ws_size, hipStream_t stream) {
  const float* hidden = (const float*)d_in[0];
  const float* obs = (const float*)d_in[1];
  const void* dones = d_in[2];
  const int* acts = (const int*)d_in[3];
  const float* w0 = (const float*)d_in[4];
  const float* b0 = (const float*)d_in[5];
  const float* ln0s = (const float*)d_in[6];
  const float* ln0b = (const float*)d_in[7];
  const float* w1 = (const float*)d_in[8];
  const float* b1 = (const float*)d_in[9];
  const float* ln1s = (const float*)d_in[10];
  const float* ln1b = (const float*)d_in[11];
  const float* wir = (const float*)d_in[12];
  const float* bir = (const float*)d_in[13];
  const float* wiz = (const float*)d_in[14];
  const float* biz = (const float*)d_in[15];
  const float* win = (const float*)d_in[16];
  const float* bin = (const float*)d_in[17];
  const float* whr = (const float*)d_in[18];
  const float* whz = (const float*)d_in[19];
  const float* whn = (const float*)d_in[20];
  const float* bhn = (const float*)d_in[21];
  const float* wout = (const float*)d_in[22];
  const float* bout = (const float*)d_in[23];

  char* ws = (char*)d_ws;
  unsigned short* bufA = (unsigned short*)(ws);                   // 64MB: obs_bf -> x1 -> x2
  unsigned short* bufB = (unsigned short*)(ws + 67108864ULL);     // 64MB: pre0 -> pre1 -> y/h
  unsigned short* gin = (unsigned short*)(ws + 134217728ULL);     // 192MB
  char* D = ws + 134217728ULL + 201326592ULL;
  unsigned short* W0at = (unsigned short*)(D);                    // 512KB
  unsigned short* W1t = (unsigned short*)(D + 524288);            // 512KB
  unsigned short* Wit = (unsigned short*)(D + 1048576);           // 1.5MB
  unsigned short* Whf = (unsigned short*)(D + 2621440);           // 1.5MB
  unsigned short* WoutT = (unsigned short*)(D + 4194304);         // 64KB
  unsigned short* w0act = (unsigned short*)(D + 4259840);         // 32KB
  float* gib = (float*)(D + 4292608);                             // 8KB
  unsigned short* hbuf = (unsigned short*)(D + 4300800);          // 512KB init h
  unsigned int* ready = (unsigned int*)(D + 5349376);             // 133KB flags
  unsigned int* flag = ready + 33280;

  (void)in_sizes; (void)n_in; (void)out_size; (void)ws_size;

  k_conv_obs<<<32768, 256, 0, stream>>>(obs, bufA, flag);
  k_prep_t<<<dim3(1024, 5), 256, 0, stream>>>(w0, w1, wir, wiz, win, W0at, W1t, Wit);
  k_prep_whf<<<3072, 256, 0, stream>>>(whr, whz, whn, Whf);
  k_prep_misc<<<1024, 256, 0, stream>>>(w0, bir, biz, bin, wout, hidden,
                                        (const int*)dones, w0act, gib, WoutT,
                                        hbuf, ready, flag);
  // encoder
  k_gemm_bt<1><<<dim3(512, 4), 256, 0, stream>>>(bufA, W0at, bufB, 512, b0, w0act, acts);
  k_ln_relu<<<16384, 256, 0, stream>>>(bufB, bufA, ln0s, ln0b);
  k_gemm_bt<0><<<dim3(512, 4), 256, 0, stream>>>(bufA, W1t, bufB, 512, b1, nullptr, nullptr);
  k_ln_relu<<<16384, 256, 0, stream>>>(bufB, bufA, ln1s, ln1b);
  // GRU input projections (biases fused)
  k_gemm_bt<0><<<dim3(512, 12), 256, 0, stream>>>(bufA, Wit, gin, 1536, gib, nullptr, nullptr);
  // sequential scan; writes new_hidden to d_out[0:262144] and y/h to bufB
  k_gru<<<256, 256, 0, stream>>>(Whf, gin, bhn, (const int*)dones,
                                 (const unsigned char*)dones, flag, hbuf, bufB,
                                 (float*)d_out, ready);
  // output head -> d_out[262144:]
  k_qout<<<512, 256, 0, stream>>>(bufB, WoutT, bout, (float*)d_out + 262144);
}